// Round 7
// baseline (257.292 us; speedup 1.0000x reference)
//
#include <hip/hip_runtime.h>
#include <math.h>

#define T_TOK 2048
#define H_DIM 1024
#define M_DIM 512
#define E_NUM 32
#define TOPK  4

#define BT    64       // tokens per tile
#define BK    32       // k per step
#define GU_BM 64       // gateup N-tile
#define DN_BH 128      // down N-tile
#define MAX_TILES 160  // sum ceil(cnt_e/64) <= 31 + 8192/64 = 159

typedef __bf16 bf16x8 __attribute__((ext_vector_type(8)));
typedef float f32x4 __attribute__((ext_vector_type(4)));
typedef unsigned short u16x4 __attribute__((ext_vector_type(4)));

__device__ __forceinline__ unsigned short f2bf(float f) {
  unsigned u = __float_as_uint(f);
  return (unsigned short)((u + 0x7fffu + ((u >> 16) & 1u)) >> 16);
}
__device__ __forceinline__ float bf2f(unsigned short h) {
  return __uint_as_float(((unsigned)h) << 16);
}
__device__ __forceinline__ f32x4 mfma16(bf16x8 a, bf16x8 b, f32x4 c) {
  return __builtin_amdgcn_mfma_f32_16x16x32_bf16(a, b, c, 0, 0, 0);
}
__device__ __forceinline__ void gload16(const void* g, void* l) {
  __builtin_amdgcn_global_load_lds(
      (const __attribute__((address_space(1))) unsigned int*)g,
      (__attribute__((address_space(3))) unsigned int*)l, 16, 0, 0);
}
__device__ __forceinline__ bf16x8 cvt8(f32x4 a, f32x4 b) {
  bf16x8 r;
  #pragma unroll
  for (int j = 0; j < 4; ++j) { r[j] = (__bf16)a[j]; r[4 + j] = (__bf16)b[j]; }
  return r;
}

// ---------------- K1: gating + x split + scatter (fused) ---------------------
__global__ __launch_bounds__(256) void gating_kernel(
    const float* __restrict__ x, const float* __restrict__ gate_w,
    unsigned short* __restrict__ xh, unsigned short* __restrict__ xl,
    float* __restrict__ topk_w, int* __restrict__ cursors,
    int* __restrict__ tok_list) {
  __shared__ float xr[H_DIM];
  __shared__ float logits[E_NUM];
  int t = blockIdx.x;
  int tid = threadIdx.x;
  const float* xrow = x + (size_t)t * H_DIM;
  float4 v = *(const float4*)(xrow + tid * 4);
  *(float4*)(xr + tid * 4) = v;
  {  // split this thread's 4 elems to hi/lo bf16
    float f[4] = {v.x, v.y, v.z, v.w};
    u16x4 hv, lv;
    #pragma unroll
    for (int j = 0; j < 4; ++j) {
      unsigned short h = f2bf(f[j]);
      hv[j] = h;
      lv[j] = f2bf(f[j] - bf2f(h));
    }
    *(u16x4*)(xh + (size_t)t * H_DIM + tid * 4) = hv;
    *(u16x4*)(xl + (size_t)t * H_DIM + tid * 4) = lv;
  }
  __syncthreads();
  int wave = tid >> 6, lane = tid & 63;
  const float4* x4 = (const float4*)xr;
  for (int e8 = 0; e8 < 8; ++e8) {
    int e = wave * 8 + e8;
    const float4* g4 = (const float4*)(gate_w + (size_t)e * H_DIM);
    float p = 0.f;
    #pragma unroll
    for (int i = 0; i < 4; ++i) {
      float4 a = x4[lane + i * 64];
      float4 b = g4[lane + i * 64];
      p += a.x * b.x + a.y * b.y + a.z * b.z + a.w * b.w;
    }
    for (int off = 32; off > 0; off >>= 1) p += __shfl_down(p, off, 64);
    if (lane == 0) logits[e] = p;
  }
  __syncthreads();
  if (tid == 0) {
    float vv[E_NUM];
    for (int e = 0; e < E_NUM; ++e) vv[e] = logits[e];
    int ids[TOPK]; float vals[TOPK];
    for (int k = 0; k < TOPK; ++k) {
      int bi = 0; float bv = -1e30f;
      for (int e = 0; e < E_NUM; ++e) if (vv[e] > bv) { bv = vv[e]; bi = e; }
      ids[k] = bi; vals[k] = bv; vv[bi] = -1e30f;
    }
    float m = vals[0];
    float w[TOPK]; float s = 0.f;
    for (int k = 0; k < TOPK; ++k) { w[k] = expf(vals[k] - m); s += w[k]; }
    float inv = 1.f / s;
    for (int k = 0; k < TOPK; ++k) {
      int g = t * TOPK + k;
      topk_w[g] = w[k] * inv;
      int slot = atomicAdd(&cursors[ids[k]], 1);
      tok_list[ids[k] * T_TOK + slot] = g;
    }
  }
}

// ---------------- K2b: tile work list ----------------------------------------
__global__ void build_tiles(const int* __restrict__ cursors,
                            int* __restrict__ n_tiles, int* __restrict__ tile_list) {
  int lane = threadIdx.x;
  int nt = 0;
  if (lane < E_NUM) nt = (cursors[lane] + BT - 1) / BT;
  int pfx = nt;
  for (int off = 1; off < 64; off <<= 1) {
    int v = __shfl_up(pfx, off, 64);
    if (lane >= off) pfx += v;
  }
  int excl = pfx - nt;
  if (lane == E_NUM - 1) *n_tiles = pfx;
  if (lane < E_NUM)
    for (int i = 0; i < nt; ++i) tile_list[excl + i] = (lane << 8) | i;
}

// ---------------- K3: gateup — DMA staging, dbuf, counted vmcnt --------------
// A LDS (bf16): elem(row,k) at ushort idx (row>>4)*512 + (k>>3)*128
//   + (row&15)*8 + (k&7). DMA chunk c=tid -> dest c*16B (lane-linear).
//   Fragment read: group g, lane l -> ushort idx g*512 + l*8 (16B/lane).
// B LDS (f32, conflict-free half-split): elem(row,k) at f32 idx
//   (row>>4)*512 + ((k>>2)&1)*256 + (k>>3)*64 + (row&15)*4 + (k&3).
//   DMA chunk c: row=(c>>7)*16+(c&15), kbase=((c>>4)&3)*8+((c>>6)&1)*4,
//   dest c*16B. Fragment read: two b128 at g*512 + l*4 and +256 (16B/lane).
__global__ __launch_bounds__(256, 3) void gateup_mfma(
    const unsigned short* __restrict__ xh, const unsigned short* __restrict__ xl,
    const float* __restrict__ w_gate, const float* __restrict__ w_up,
    const float* __restrict__ topk_w,
    const int* __restrict__ cursors, const int* __restrict__ tok_list,
    const int* __restrict__ n_tiles, const int* __restrict__ tile_list,
    unsigned short* __restrict__ mixed) {
  if (blockIdx.y >= *n_tiles) return;
  int tid = threadIdx.x;
  int entry = tile_list[blockIdx.y];
  int e = entry >> 8, tile = entry & 255;
  int cnt = cursors[e];
  int m0 = blockIdx.x * GU_BM;

  __shared__ unsigned short Ah[2][BT * BK];   // 4 KB per buf
  __shared__ unsigned short Al[2][BT * BK];   // 4 KB per buf
  __shared__ float Gs[2][GU_BM * BK];         // 8 KB per buf
  __shared__ float Us[2][GU_BM * BK];         // 8 KB per buf
  __shared__ int   ent[BT];
  __shared__ float rw[BT];

  if (tid < BT) {
    int idx = tile * BT + tid;
    int en = (idx < cnt) ? tok_list[e * T_TOK + idx] : -1;
    ent[tid] = en;
    rw[tid]  = (en >= 0) ? topk_w[en] : 0.f;
  }
  __syncthreads();

  // A staging: chunk c = tid; row=(c>>6)*16+(c&15), k-octet=(c>>4)&3
  int arow = ((tid >> 6) << 4) + (tid & 15);
  int askq = (tid >> 4) & 3;
  int aen = ent[arow]; if (aen < 0) aen = ent[0];
  const unsigned short* gAh = xh + (size_t)(aen >> 2) * H_DIM + askq * 8;
  const unsigned short* gAl = xl + (size_t)(aen >> 2) * H_DIM + askq * 8;

  // B staging: chunks c0=tid, c1=tid+256 for each of G,U
  int c0 = tid, c1 = tid + 256;
  int br0 = ((c0 >> 7) << 4) + (c0 & 15);
  int bk0 = ((c0 >> 4) & 3) * 8 + ((c0 >> 6) & 1) * 4;
  int br1 = ((c1 >> 7) << 4) + (c1 & 15);
  int bk1 = ((c1 >> 4) & 3) * 8 + ((c1 >> 6) & 1) * 4;
  const float* gG0 = w_gate + ((size_t)e * M_DIM + m0 + br0) * H_DIM + bk0;
  const float* gG1 = w_gate + ((size_t)e * M_DIM + m0 + br1) * H_DIM + bk1;
  const float* gU0 = w_up   + ((size_t)e * M_DIM + m0 + br0) * H_DIM + bk0;
  const float* gU1 = w_up   + ((size_t)e * M_DIM + m0 + br1) * H_DIM + bk1;

  int lane = tid & 63, wid = tid >> 6;
  int wr = (wid >> 1) * 32;  // 0,32
  int wc = (wid & 1) * 32;   // 0,32
  int l8 = lane * 8;
  int l4 = lane * 4;

  f32x4 accg[2][2] = {}; f32x4 accu[2][2] = {};

#define GU_STAGE(B, K0) { \
    gload16(gAh + (K0), &Ah[B][tid * 8]); \
    gload16(gAl + (K0), &Al[B][tid * 8]); \
    gload16(gG0 + (K0), &Gs[B][c0 * 4]); \
    gload16(gG1 + (K0), &Gs[B][c1 * 4]); \
    gload16(gU0 + (K0), &Us[B][c0 * 4]); \
    gload16(gU1 + (K0), &Us[B][c1 * 4]); }

#define GU_COMPUTE(B) { \
    int ab = (wr >> 4) * 512 + l8; \
    bf16x8 a0h = *(const bf16x8*)&Ah[B][ab]; \
    bf16x8 a1h = *(const bf16x8*)&Ah[B][ab + 512]; \
    bf16x8 a0l = *(const bf16x8*)&Al[B][ab]; \
    bf16x8 a1l = *(const bf16x8*)&Al[B][ab + 512]; \
    _Pragma("unroll") \
    for (int nf = 0; nf < 2; ++nf) { \
      int nb = ((wc >> 4) + nf) * 512 + l4; \
      bf16x8 g = cvt8(*(const f32x4*)&Gs[B][nb], *(const f32x4*)&Gs[B][nb + 256]); \
      bf16x8 u = cvt8(*(const f32x4*)&Us[B][nb], *(const f32x4*)&Us[B][nb + 256]); \
      accg[0][nf] = mfma16(a0h, g, accg[0][nf]); \
      accg[0][nf] = mfma16(a0l, g, accg[0][nf]); \
      accg[1][nf] = mfma16(a1h, g, accg[1][nf]); \
      accg[1][nf] = mfma16(a1l, g, accg[1][nf]); \
      accu[0][nf] = mfma16(a0h, u, accu[0][nf]); \
      accu[0][nf] = mfma16(a0l, u, accu[0][nf]); \
      accu[1][nf] = mfma16(a1h, u, accu[1][nf]); \
      accu[1][nf] = mfma16(a1l, u, accu[1][nf]); } }

#define GU_PHASE(CUR, NXT, KNEXT) { \
    if ((KNEXT) < H_DIM) { \
      GU_STAGE(NXT, KNEXT); \
      asm volatile("s_waitcnt vmcnt(6)" ::: "memory"); \
    } else { \
      asm volatile("s_waitcnt vmcnt(0)" ::: "memory"); \
    } \
    __builtin_amdgcn_s_barrier(); \
    asm volatile("" ::: "memory"); \
    __builtin_amdgcn_sched_barrier(0); \
    GU_COMPUTE(CUR); \
    __builtin_amdgcn_sched_barrier(0); \
    asm volatile("" ::: "memory"); \
    __builtin_amdgcn_s_barrier(); }

  GU_STAGE(0, 0);
  const int NK = H_DIM / BK;  // 32, even
  for (int ks = 0; ks < NK; ks += 2) {
    GU_PHASE(0, 1, (ks + 1) * BK);
    GU_PHASE(1, 0, (ks + 2) * BK);
  }

  #pragma unroll
  for (int mf = 0; mf < 2; ++mf) {
    #pragma unroll
    for (int j = 0; j < 4; ++j) {
      int tr = wr + mf * 16 + (lane >> 4) * 4 + j;
      int en = ent[tr];
      if (en < 0) continue;
      float w = rw[tr];
      #pragma unroll
      for (int nf = 0; nf < 2; ++nf) {
        float g = accg[mf][nf][j], u = accu[mf][nf][j];
        float val = (g / (1.f + __expf(-g))) * u * w;
        __bf16 bv = (__bf16)val;
        mixed[(size_t)en * M_DIM + m0 + wc + nf * 16 + (lane & 15)] =
            *(unsigned short*)&bv;
      }
    }
  }
}

// ---------------- K4: down — DMA staging, dbuf, counted vmcnt ----------------
__global__ __launch_bounds__(256, 4) void down_mfma(
    const float* __restrict__ w_down, const unsigned short* __restrict__ mixed,
    const int* __restrict__ cursors, const int* __restrict__ tok_list,
    const int* __restrict__ n_tiles, const int* __restrict__ tile_list,
    float* __restrict__ out) {
  if (blockIdx.y >= *n_tiles) return;
  int tid = threadIdx.x;
  int entry = tile_list[blockIdx.y];
  int e = entry >> 8, tile = entry & 255;
  int cnt = cursors[e];
  int h0 = blockIdx.x * DN_BH;

  __shared__ unsigned short As[2][BT * BK];   // 4 KB per buf
  __shared__ float Bs[2][DN_BH * BK];         // 16 KB per buf
  __shared__ int ent[BT];

  if (tid < BT) {
    int idx = tile * BT + tid;
    ent[tid] = (idx < cnt) ? tok_list[e * T_TOK + idx] : -1;
  }
  __syncthreads();

  // A: chunk c = tid
  int arow = ((tid >> 6) << 4) + (tid & 15);
  int askq = (tid >> 4) & 3;
  int aen = ent[arow]; if (aen < 0) aen = ent[0];
  const unsigned short* gA = mixed + (size_t)aen * M_DIM + askq * 8;

  // B: 4 chunks c = tid + 256*i (conflict-free half-split layout)
  const float* gB0; const float* gB1; const float* gB2; const float* gB3;
  {
    int c = tid;
    gB0 = w_down + ((size_t)e * H_DIM + h0 + ((c >> 7) << 4) + (c & 15)) * M_DIM
          + ((c >> 4) & 3) * 8 + ((c >> 6) & 1) * 4;
    c = tid + 256;
    gB1 = w_down + ((size_t)e * H_DIM + h0 + ((c >> 7) << 4) + (c & 15)) * M_DIM
          + ((c >> 4) & 3) * 8 + ((c >> 6) & 1) * 4;
    c = tid + 512;
    gB2 = w_down + ((size_t)e * H_DIM + h0 + ((c >> 7) << 4) + (c & 15)) * M_DIM
          + ((c >> 4) & 3) * 8 + ((c >> 6) & 1) * 4;
    c = tid + 768;
    gB3 = w_down + ((size_t)e * H_DIM + h0 + ((c >> 7) << 4) + (c & 15)) * M_DIM
          + ((c >> 4) & 3) * 8 + ((c >> 6) & 1) * 4;
  }

  int lane = tid & 63, wid = tid >> 6;
  int wr = (wid >> 1) * 32;  // 0,32
  int wc = (wid & 1) * 64;   // 0,64
  int l8 = lane * 8;
  int l4 = lane * 4;

  f32x4 acc[2][4] = {};

#define DN_STAGE(B, K0) { \
    gload16(gA + (K0), &As[B][tid * 8]); \
    gload16(gB0 + (K0), &Bs[B][tid * 4]); \
    gload16(gB1 + (K0), &Bs[B][(tid + 256) * 4]); \
    gload16(gB2 + (K0), &Bs[B][(tid + 512) * 4]); \
    gload16(gB3 + (K0), &Bs[B][(tid + 768) * 4]); }

#define DN_COMPUTE(B) { \
    int ab = (wr >> 4) * 512 + l8; \
    bf16x8 a0 = *(const bf16x8*)&As[B][ab]; \
    bf16x8 a1 = *(const bf16x8*)&As[B][ab + 512]; \
    _Pragma("unroll") \
    for (int nf = 0; nf < 4; ++nf) { \
      int nb = ((wc >> 4) + nf) * 512 + l4; \
      bf16x8 b = cvt8(*(const f32x4*)&Bs[B][nb], *(const f32x4*)&Bs[B][nb + 256]); \
      acc[0][nf] = mfma16(a0, b, acc[0][nf]); \
      acc[1][nf] = mfma16(a1, b, acc[1][nf]); } }

#define DN_PHASE(CUR, NXT, KNEXT) { \
    if ((KNEXT) < M_DIM) { \
      DN_STAGE(NXT, KNEXT); \
      asm volatile("s_waitcnt vmcnt(5)" ::: "memory"); \
    } else { \
      asm volatile("s_waitcnt vmcnt(0)" ::: "memory"); \
    } \
    __builtin_amdgcn_s_barrier(); \
    asm volatile("" ::: "memory"); \
    __builtin_amdgcn_sched_barrier(0); \
    DN_COMPUTE(CUR); \
    __builtin_amdgcn_sched_barrier(0); \
    asm volatile("" ::: "memory"); \
    __builtin_amdgcn_s_barrier(); }

  DN_STAGE(0, 0);
  const int NK = M_DIM / BK;  // 16, even
  for (int ks = 0; ks < NK; ks += 2) {
    DN_PHASE(0, 1, (ks + 1) * BK);
    DN_PHASE(1, 0, (ks + 2) * BK);
  }

  #pragma unroll
  for (int mf = 0; mf < 2; ++mf) {
    #pragma unroll
    for (int j = 0; j < 4; ++j) {
      int tr = wr + mf * 16 + (lane >> 4) * 4 + j;
      int en = ent[tr];
      if (en < 0) continue;
      int t = en >> 2;
      #pragma unroll
      for (int nf = 0; nf < 4; ++nf)
        atomicAdd(&out[(size_t)t * H_DIM + h0 + wc + nf * 16 + (lane & 15)],
                  acc[mf][nf][j]);
    }
  }
}

extern "C" void kernel_launch(void* const* d_in, const int* in_sizes, int n_in,
                              void* d_out, int out_size, void* d_ws, size_t ws_size,
                              hipStream_t stream) {
  const float* x      = (const float*)d_in[0];
  const float* gate_w = (const float*)d_in[1];
  const float* w_gate = (const float*)d_in[2];
  const float* w_up   = (const float*)d_in[3];
  const float* w_down = (const float*)d_in[4];
  float* out = (float*)d_out;

  char* ws = (char*)d_ws;
  size_t off = 0;
  float* topk_w    = (float*)(ws + off); off += (size_t)T_TOK * TOPK * 4;
  int*   cursors   = (int*)(ws + off);   off += 256;
  int*   n_tiles   = (int*)(ws + off);   off += 64;
  int*   tile_list = (int*)(ws + off);   off += MAX_TILES * 4 + 64;
  int*   tok_list  = (int*)(ws + off);   off += (size_t)E_NUM * T_TOK * 4;
  unsigned short* x_hi  = (unsigned short*)(ws + off); off += (size_t)T_TOK * H_DIM * 2;
  unsigned short* x_lo  = (unsigned short*)(ws + off); off += (size_t)T_TOK * H_DIM * 2;
  unsigned short* mixed = (unsigned short*)(ws + off); off += (size_t)T_TOK * TOPK * M_DIM * 2;

  hipMemsetAsync(cursors, 0, E_NUM * sizeof(int), stream);
  hipMemsetAsync(out, 0, (size_t)T_TOK * H_DIM * sizeof(float), stream);

  gating_kernel<<<T_TOK, 256, 0, stream>>>(x, gate_w, x_hi, x_lo, topk_w,
                                           cursors, tok_list);
  build_tiles<<<1, 64, 0, stream>>>(cursors, n_tiles, tile_list);
  gateup_mfma<<<dim3(M_DIM / GU_BM, MAX_TILES), 256, 0, stream>>>(
      x_hi, x_lo, w_gate, w_up, topk_w, cursors, tok_list, n_tiles, tile_list, mixed);
  down_mfma<<<dim3(H_DIM / DN_BH, MAX_TILES), 256, 0, stream>>>(
      w_down, mixed, cursors, tok_list, n_tiles, tile_list, out);
}

// Round 8
// 176.641 us; speedup vs baseline: 1.4566x; 1.4566x over previous
//
#include <hip/hip_runtime.h>
#include <math.h>

#define T_TOK 2048
#define H_DIM 1024
#define M_DIM 512
#define E_NUM 32
#define TOPK  4

#define GU_BT 128      // gateup tokens per tile
#define DN_BT 64       // down tokens per tile
#define BK    64       // k per step
#define GU_BM 64       // gateup N-tile
#define DN_BH 128      // down N-tile
#define GU_MAXT 96     // sum ceil(cnt/128) <= 32 + 8192/128 = 96
#define DN_MAXT 160    // sum ceil(cnt/64)  <= 31 + 8192/64  = 159

typedef __bf16 bf16x8 __attribute__((ext_vector_type(8)));
typedef float f32x4 __attribute__((ext_vector_type(4)));
typedef unsigned short u16x8 __attribute__((ext_vector_type(8)));
typedef unsigned short u16x4 __attribute__((ext_vector_type(4)));

__device__ __forceinline__ unsigned short f2bf(float f) {
  unsigned u = __float_as_uint(f);
  return (unsigned short)((u + 0x7fffu + ((u >> 16) & 1u)) >> 16);
}
__device__ __forceinline__ f32x4 mfma16(bf16x8 a, bf16x8 b, f32x4 c) {
  return __builtin_amdgcn_mfma_f32_16x16x32_bf16(a, b, c, 0, 0, 0);
}

// ---------------- K1: gating + x->bf16 + scatter (fused) ---------------------
__global__ __launch_bounds__(256) void gating_kernel(
    const float* __restrict__ x, const float* __restrict__ gate_w,
    unsigned short* __restrict__ xh,
    float* __restrict__ topk_w, int* __restrict__ cursors,
    int* __restrict__ tok_list) {
  __shared__ float xr[H_DIM];
  __shared__ float logits[E_NUM];
  int t = blockIdx.x;
  int tid = threadIdx.x;
  const float* xrow = x + (size_t)t * H_DIM;
  float4 v = *(const float4*)(xrow + tid * 4);
  *(float4*)(xr + tid * 4) = v;
  {  // bf16-round this thread's 4 elems
    float f[4] = {v.x, v.y, v.z, v.w};
    u16x4 hv;
    #pragma unroll
    for (int j = 0; j < 4; ++j) hv[j] = f2bf(f[j]);
    *(u16x4*)(xh + (size_t)t * H_DIM + tid * 4) = hv;
  }
  __syncthreads();
  int wave = tid >> 6, lane = tid & 63;
  const float4* x4 = (const float4*)xr;
  for (int e8 = 0; e8 < 8; ++e8) {
    int e = wave * 8 + e8;
    const float4* g4 = (const float4*)(gate_w + (size_t)e * H_DIM);
    float p = 0.f;
    #pragma unroll
    for (int i = 0; i < 4; ++i) {
      float4 a = x4[lane + i * 64];
      float4 b = g4[lane + i * 64];
      p += a.x * b.x + a.y * b.y + a.z * b.z + a.w * b.w;
    }
    for (int off = 32; off > 0; off >>= 1) p += __shfl_down(p, off, 64);
    if (lane == 0) logits[e] = p;
  }
  __syncthreads();
  if (tid == 0) {
    float vv[E_NUM];
    for (int e = 0; e < E_NUM; ++e) vv[e] = logits[e];
    int ids[TOPK]; float vals[TOPK];
    for (int k = 0; k < TOPK; ++k) {
      int bi = 0; float bv = -1e30f;
      for (int e = 0; e < E_NUM; ++e) if (vv[e] > bv) { bv = vv[e]; bi = e; }
      ids[k] = bi; vals[k] = bv; vv[bi] = -1e30f;
    }
    float m = vals[0];
    float w[TOPK]; float s = 0.f;
    for (int k = 0; k < TOPK; ++k) { w[k] = expf(vals[k] - m); s += w[k]; }
    float inv = 1.f / s;
    for (int k = 0; k < TOPK; ++k) {
      int g = t * TOPK + k;
      topk_w[g] = w[k] * inv;
      int slot = atomicAdd(&cursors[ids[k]], 1);
      tok_list[ids[k] * T_TOK + slot] = g;
    }
  }
}

// ---------------- K2b: tile work lists (both BT=128 and BT=64) ---------------
__global__ void build_tiles(const int* __restrict__ cursors,
                            int* __restrict__ n_tiles,
                            int* __restrict__ tl_gu, int* __restrict__ tl_dn) {
  int lane = threadIdx.x;
  int c = (lane < E_NUM) ? cursors[lane] : 0;
  {
    int nt = (c + GU_BT - 1) / GU_BT;
    int pfx = nt;
    for (int off = 1; off < 64; off <<= 1) {
      int v = __shfl_up(pfx, off, 64);
      if (lane >= off) pfx += v;
    }
    if (lane == E_NUM - 1) n_tiles[0] = pfx;
    int excl = pfx - nt;
    if (lane < E_NUM)
      for (int i = 0; i < nt; ++i) tl_gu[excl + i] = (lane << 8) | i;
  }
  {
    int nt = (c + DN_BT - 1) / DN_BT;
    int pfx = nt;
    for (int off = 1; off < 64; off <<= 1) {
      int v = __shfl_up(pfx, off, 64);
      if (lane >= off) pfx += v;
    }
    if (lane == E_NUM - 1) n_tiles[1] = pfx;
    int excl = pfx - nt;
    if (lane < E_NUM)
      for (int i = 0; i < nt; ++i) tl_dn[excl + i] = (lane << 8) | i;
  }
}

// ---------------- K3: gateup — 128x64, BK=64, single-bf16-A ------------------
// LDS layout (per matrix): chunk(row, ko) [ko = k-octet 0..7] at ushort addr
//   row*64 + (ko ^ (row&7))*8. Staging writes and fragment reads both <=2-way
//   per 16-lane phase (free). Fragment read (rows R..R+15, k-frag kf):
//   addr = (R+(lane&15))*64 + ((kf*4 + (lane>>4)) ^ (lane&7))*8.
__global__ __launch_bounds__(512) void gateup_mfma(
    const unsigned short* __restrict__ xh,
    const float* __restrict__ w_gate, const float* __restrict__ w_up,
    const float* __restrict__ topk_w,
    const int* __restrict__ cursors, const int* __restrict__ tok_list,
    const int* __restrict__ n_tiles, const int* __restrict__ tile_list,
    unsigned short* __restrict__ mixed) {
  if (blockIdx.y >= n_tiles[0]) return;
  int tid = threadIdx.x;
  int entry = tile_list[blockIdx.y];
  int e = entry >> 8, tile = entry & 255;
  int cnt = cursors[e];
  int m0 = blockIdx.x * GU_BM;

  __shared__ unsigned short As[GU_BT * BK];  // 16 KB
  __shared__ unsigned short Gs[GU_BM * BK];  // 8 KB
  __shared__ unsigned short Us[GU_BM * BK];  // 8 KB
  __shared__ int   ent[GU_BT];
  __shared__ float rw[GU_BT];

  if (tid < GU_BT) {
    int idx = tile * GU_BT + tid;
    int en = (idx < cnt) ? tok_list[e * T_TOK + idx] : -1;
    ent[tid] = en;
    rw[tid]  = (en >= 0) ? topk_w[en] : 0.f;
  }
  __syncthreads();

  // A staging: 128 rows x 4 thr/row, 32B (2 chunks) per thread
  int arow = tid >> 2, atq = tid & 3;
  int aen = ent[arow]; if (aen < 0) aen = ent[0];
  const unsigned short* gA = xh + (size_t)(aen >> 2) * H_DIM + atq * 16;
  int aoff0 = arow * 64 + ((2 * atq) ^ (arow & 7)) * 8;
  int aoff1 = arow * 64 + ((2 * atq + 1) ^ (arow & 7)) * 8;

  // B staging: 64 rows x 8 thr/row, 32B f32 -> 1 bf16 chunk per thread
  int brow = tid >> 3, bko = tid & 7;
  const float* gG = w_gate + ((size_t)e * M_DIM + m0 + brow) * H_DIM + bko * 8;
  const float* gU = w_up   + ((size_t)e * M_DIM + m0 + brow) * H_DIM + bko * 8;
  int boff = brow * 64 + (bko ^ (brow & 7)) * 8;

  int lane = tid & 63, wid = tid >> 6;
  int wr = (wid >> 1) * 32;  // 0,32,64,96
  int wc = (wid & 1) * 32;   // 0,32
  int l15_64 = (lane & 15) * 64;
  int xk0 = (((lane >> 4)) ^ (lane & 7)) * 8;
  int xk1 = ((4 + (lane >> 4)) ^ (lane & 7)) * 8;

  f32x4 accg[2][2] = {}; f32x4 accu[2][2] = {};
  u16x8 ra0, ra1; float fg[8], fu[8];

#define GU_LOAD(K0) { \
    ra0 = *(const u16x8*)(gA + (K0)); \
    ra1 = *(const u16x8*)(gA + (K0) + 8); \
    *(float4*)(fg)     = *(const float4*)(gG + (K0)); \
    *(float4*)(fg + 4) = *(const float4*)(gG + (K0) + 4); \
    *(float4*)(fu)     = *(const float4*)(gU + (K0)); \
    *(float4*)(fu + 4) = *(const float4*)(gU + (K0) + 4); }

#define GU_STORE() { \
    *(u16x8*)&As[aoff0] = ra0; \
    *(u16x8*)&As[aoff1] = ra1; \
    u16x8 gq, uq; \
    _Pragma("unroll") \
    for (int j = 0; j < 8; ++j) { gq[j] = f2bf(fg[j]); uq[j] = f2bf(fu[j]); } \
    *(u16x8*)&Gs[boff] = gq; \
    *(u16x8*)&Us[boff] = uq; }

#define GU_COMP(XK) { \
    int ab = wr * 64 + l15_64 + (XK); \
    int nb = wc * 64 + l15_64 + (XK); \
    bf16x8 a0 = *(const bf16x8*)&As[ab]; \
    bf16x8 a1 = *(const bf16x8*)&As[ab + 1024]; \
    bf16x8 g0 = *(const bf16x8*)&Gs[nb]; \
    bf16x8 g1 = *(const bf16x8*)&Gs[nb + 1024]; \
    bf16x8 u0 = *(const bf16x8*)&Us[nb]; \
    bf16x8 u1 = *(const bf16x8*)&Us[nb + 1024]; \
    accg[0][0] = mfma16(a0, g0, accg[0][0]); \
    accg[0][1] = mfma16(a0, g1, accg[0][1]); \
    accg[1][0] = mfma16(a1, g0, accg[1][0]); \
    accg[1][1] = mfma16(a1, g1, accg[1][1]); \
    accu[0][0] = mfma16(a0, u0, accu[0][0]); \
    accu[0][1] = mfma16(a0, u1, accu[0][1]); \
    accu[1][0] = mfma16(a1, u0, accu[1][0]); \
    accu[1][1] = mfma16(a1, u1, accu[1][1]); }

  GU_LOAD(0);
  const int NK = H_DIM / BK;  // 16
  for (int ks = 0; ks < NK; ++ks) {
    __syncthreads();          // prev compute done reading LDS
    GU_STORE();
    __syncthreads();          // staging visible
    if (ks + 1 < NK) GU_LOAD((ks + 1) * BK);  // in flight across compute
    GU_COMP(xk0);
    GU_COMP(xk1);
  }

  #pragma unroll
  for (int mf = 0; mf < 2; ++mf) {
    #pragma unroll
    for (int j = 0; j < 4; ++j) {
      int tr = wr + mf * 16 + (lane >> 4) * 4 + j;
      int en = ent[tr];
      if (en < 0) continue;
      float w = rw[tr];
      #pragma unroll
      for (int nf = 0; nf < 2; ++nf) {
        float g = accg[mf][nf][j], u = accu[mf][nf][j];
        float val = (g / (1.f + __expf(-g))) * u * w;
        mixed[(size_t)en * M_DIM + m0 + wc + nf * 16 + (lane & 15)] = f2bf(val);
      }
    }
  }
}

// ---------------- K4: down — 64x128, BK=64 -----------------------------------
__global__ __launch_bounds__(512) void down_mfma(
    const float* __restrict__ w_down, const unsigned short* __restrict__ mixed,
    const int* __restrict__ cursors, const int* __restrict__ tok_list,
    const int* __restrict__ n_tiles, const int* __restrict__ tile_list,
    float* __restrict__ out) {
  if (blockIdx.y >= n_tiles[1]) return;
  int tid = threadIdx.x;
  int entry = tile_list[blockIdx.y];
  int e = entry >> 8, tile = entry & 255;
  int cnt = cursors[e];
  int h0 = blockIdx.x * DN_BH;

  __shared__ unsigned short As[DN_BT * BK];  // 8 KB
  __shared__ unsigned short Bs[DN_BH * BK];  // 16 KB
  __shared__ int ent[DN_BT];

  if (tid < DN_BT) {
    int idx = tile * DN_BT + tid;
    ent[tid] = (idx < cnt) ? tok_list[e * T_TOK + idx] : -1;
  }
  __syncthreads();

  // A staging: 64 rows x 8 thr/row, 1 chunk per thread
  int arow = tid >> 3, ako = tid & 7;
  int aen = ent[arow]; if (aen < 0) aen = ent[0];
  const unsigned short* gA = mixed + (size_t)aen * M_DIM + ako * 8;
  int aoff = arow * 64 + (ako ^ (arow & 7)) * 8;

  // B staging: 128 rows x 4 thr/row, 64B f32 -> 2 bf16 chunks per thread
  int brow = tid >> 2, btq = tid & 3;
  const float* gB = w_down + ((size_t)e * H_DIM + h0 + brow) * M_DIM + btq * 16;
  int boff0 = brow * 64 + ((2 * btq) ^ (brow & 7)) * 8;
  int boff1 = brow * 64 + ((2 * btq + 1) ^ (brow & 7)) * 8;

  int lane = tid & 63, wid = tid >> 6;
  int wr = (wid >> 2) * 32;  // 0,32
  int wc = (wid & 3) * 32;   // 0,32,64,96
  int l15_64 = (lane & 15) * 64;
  int xk0 = (((lane >> 4)) ^ (lane & 7)) * 8;
  int xk1 = ((4 + (lane >> 4)) ^ (lane & 7)) * 8;

  f32x4 acc[2][2] = {};
  u16x8 ra; float fb[16];

#define DN_LOAD(K0) { \
    ra = *(const u16x8*)(gA + (K0)); \
    *(float4*)(fb)      = *(const float4*)(gB + (K0)); \
    *(float4*)(fb + 4)  = *(const float4*)(gB + (K0) + 4); \
    *(float4*)(fb + 8)  = *(const float4*)(gB + (K0) + 8); \
    *(float4*)(fb + 12) = *(const float4*)(gB + (K0) + 12); }

#define DN_STORE() { \
    *(u16x8*)&As[aoff] = ra; \
    u16x8 b0q, b1q; \
    _Pragma("unroll") \
    for (int j = 0; j < 8; ++j) { b0q[j] = f2bf(fb[j]); b1q[j] = f2bf(fb[8 + j]); } \
    *(u16x8*)&Bs[boff0] = b0q; \
    *(u16x8*)&Bs[boff1] = b1q; }

#define DN_COMP(XK) { \
    int ab = wr * 64 + l15_64 + (XK); \
    int nb = wc * 64 + l15_64 + (XK); \
    bf16x8 a0 = *(const bf16x8*)&As[ab]; \
    bf16x8 a1 = *(const bf16x8*)&As[ab + 1024]; \
    bf16x8 b0 = *(const bf16x8*)&Bs[nb]; \
    bf16x8 b1 = *(const bf16x8*)&Bs[nb + 1024]; \
    acc[0][0] = mfma16(a0, b0, acc[0][0]); \
    acc[0][1] = mfma16(a0, b1, acc[0][1]); \
    acc[1][0] = mfma16(a1, b0, acc[1][0]); \
    acc[1][1] = mfma16(a1, b1, acc[1][1]); }

  DN_LOAD(0);
  const int NK = M_DIM / BK;  // 8
  for (int ks = 0; ks < NK; ++ks) {
    __syncthreads();
    DN_STORE();
    __syncthreads();
    if (ks + 1 < NK) DN_LOAD((ks + 1) * BK);
    DN_COMP(xk0);
    DN_COMP(xk1);
  }

  #pragma unroll
  for (int mf = 0; mf < 2; ++mf) {
    #pragma unroll
    for (int j = 0; j < 4; ++j) {
      int tr = wr + mf * 16 + (lane >> 4) * 4 + j;
      int en = ent[tr];
      if (en < 0) continue;
      int t = en >> 2;
      #pragma unroll
      for (int nf = 0; nf < 2; ++nf)
        atomicAdd(&out[(size_t)t * H_DIM + h0 + wc + nf * 16 + (lane & 15)],
                  acc[mf][nf][j]);
    }
  }
}

extern "C" void kernel_launch(void* const* d_in, const int* in_sizes, int n_in,
                              void* d_out, int out_size, void* d_ws, size_t ws_size,
                              hipStream_t stream) {
  const float* x      = (const float*)d_in[0];
  const float* gate_w = (const float*)d_in[1];
  const float* w_gate = (const float*)d_in[2];
  const float* w_up   = (const float*)d_in[3];
  const float* w_down = (const float*)d_in[4];
  float* out = (float*)d_out;

  char* ws = (char*)d_ws;
  size_t off = 0;
  float* topk_w  = (float*)(ws + off); off += (size_t)T_TOK * TOPK * 4;
  int*   cursors = (int*)(ws + off);   off += 256;
  int*   n_tiles = (int*)(ws + off);   off += 64;
  int*   tl_gu   = (int*)(ws + off);   off += GU_MAXT * 4 + 64;
  int*   tl_dn   = (int*)(ws + off);   off += DN_MAXT * 4 + 64;
  int*   tok_list = (int*)(ws + off);  off += (size_t)E_NUM * T_TOK * 4;
  unsigned short* x_hi  = (unsigned short*)(ws + off); off += (size_t)T_TOK * H_DIM * 2;
  unsigned short* mixed = (unsigned short*)(ws + off); off += (size_t)T_TOK * TOPK * M_DIM * 2;

  hipMemsetAsync(cursors, 0, E_NUM * sizeof(int), stream);
  hipMemsetAsync(out, 0, (size_t)T_TOK * H_DIM * sizeof(float), stream);

  gating_kernel<<<T_TOK, 256, 0, stream>>>(x, gate_w, x_hi, topk_w,
                                           cursors, tok_list);
  build_tiles<<<1, 64, 0, stream>>>(cursors, n_tiles, tl_gu, tl_dn);
  gateup_mfma<<<dim3(M_DIM / GU_BM, GU_MAXT), 512, 0, stream>>>(
      x_hi, w_gate, w_up, topk_w, cursors, tok_list, n_tiles, tl_gu, mixed);
  down_mfma<<<dim3(H_DIM / DN_BH, DN_MAXT), 512, 0, stream>>>(
      w_down, mixed, cursors, tok_list, n_tiles, tl_dn, out);
}